// Round 2
// baseline (989.876 us; speedup 1.0000x reference)
//
#include <hip/hip_runtime.h>
#include <hip/hip_bf16.h>
#include <math.h>

#define NS 5184   // 72*72
#define NPIX 81   // 9*9 pixels per image

// ---------------------------------------------------------------------------
// K1: blocks 0..191 = FISTA (one (batch,channel) pair per block, all in LDS,
//     using the exact separable structure mat = gp (x) gp).
//     block 192 = all the small paths (w, y, z) that do not depend on FISTA.
// ---------------------------------------------------------------------------
__global__ __launch_bounds__(256) void cs_fista_small(
    const float* __restrict__ x, const float* __restrict__ mat,
    const float* __restrict__ wy1, const float* __restrict__ by1,
    const float* __restrict__ wy7, const float* __restrict__ by7,
    const float* __restrict__ bn_y_g, const float* __restrict__ bn_y_b,
    const float* __restrict__ ww1, const float* __restrict__ bw1,
    const float* __restrict__ wd1, const float* __restrict__ bnd1_g, const float* __restrict__ bnd1_b,
    const float* __restrict__ wd2, const float* __restrict__ bnd2_g, const float* __restrict__ bnd2_b,
    const float* __restrict__ wu1, const float* __restrict__ bnu1_g, const float* __restrict__ bnu1_b,
    const float* __restrict__ wu2,
    float* __restrict__ ws_y, float* __restrict__ bns, float* __restrict__ out)
{
  __shared__ __align__(16) float smem[15872];   // 62 KB, unioned between the two paths
  const int tid = threadIdx.x;
  const int blk = blockIdx.x;

  if (blk < 192) {
    // ------------------------- FISTA -------------------------
    const int bb = blk / 3, ch = blk % 3;
    float* Y   = smem;           // 5184  y_tmp (momentum state)
    float* YL  = smem + 5184;    // 5184  y_last (= y_new of prev iter)
    float* W1  = smem + 10368;   // 648   [a*9+j] = sum_b Y[a,b] gp[b,j]   (also reduce scratch)
    float* T2  = smem + 11016;   // 648   [a*9+j] = sum_i gp[a,i] R[i,j]   (also reduce scratch)
    float* GP  = smem + 11664;   // 648   gp[b*9+j]
    float* GPT = smem + 12312;   // 648   gp transposed [j*72+b]
    float* Rm  = smem + 12960;   // 81
    float* IM  = smem + 13044;   // 81

    for (int k = tid; k < 648; k += 256) {
      int a = k / 9, i = k % 9;
      // mat[(a,a),(i,i)] = gp[a,i]^2 exactly (Kronecker structure, gp > 0)
      float v = sqrtf(mat[a*73*81 + i*10]);
      GP[k] = v;
      GPT[i*72 + a] = v;
    }
    for (int k = tid; k < NS; k += 256) { Y[k] = 0.f; YL[k] = 0.f; }
    if (tid < 81) IM[tid] = x[(bb*81 + tid)*3 + ch];
    __syncthreads();

    float t = 1.f;
    for (int it = 0; it < 100; ++it) {
      // stage 1: W1[a,j] = sum_b Y[a,b] * gp[b,j]  (contiguous float4 dots)
      for (int k = tid; k < 648; k += 256) {
        int a = k / 9, j = k % 9;
        const float4* yr = (const float4*)(Y + a*72);
        const float4* gr = (const float4*)(GPT + j*72);
        float acc = 0.f;
        #pragma unroll
        for (int q = 0; q < 18; ++q) {
          float4 yv = yr[q], gv = gr[q];
          acc = fmaf(yv.x, gv.x, acc);
          acc = fmaf(yv.y, gv.y, acc);
          acc = fmaf(yv.z, gv.z, acc);
          acc = fmaf(yv.w, gv.w, acc);
        }
        W1[k] = acc;
      }
      __syncthreads();
      // stage 2: Rm[i,j] = IM[i,j] - sum_a gp[a,i] * W1[a,j]
      if (tid < 81) {
        int i = tid / 9, j = tid % 9;
        float acc = 0.f;
        for (int a = 0; a < 72; ++a) acc = fmaf(GP[a*9 + i], W1[a*9 + j], acc);
        Rm[tid] = IM[tid] - acc;
      }
      __syncthreads();
      // stage 3: T2[a,j] = sum_i gp[a,i] * Rm[i,j]
      for (int k = tid; k < 648; k += 256) {
        int a = k / 9, j = k % 9;
        float acc = 0.f;
        #pragma unroll
        for (int i = 0; i < 9; ++i) acc = fmaf(GP[a*9 + i], Rm[i*9 + j], acc);
        T2[k] = acc;
      }
      __syncthreads();
      // stage 4: re[a,b] = sum_j gp[b,j] T2[a,j]; soft-threshold + momentum.
      const float tn  = 0.5f * (1.f + sqrtf(1.f + 4.f*t*t));
      const float mom = (t - 1.f) / tn;
      for (int k = tid; k < 1296; k += 256) {   // quads of 4 consecutive s
        const int s0 = 4*k;
        const int a = s0 / 72, b = s0 % 72;     // b % 4 == 0 -> 16B aligned gp rows
        float g[36];
        const float4* gp4 = (const float4*)(GP + b*9);
        #pragma unroll
        for (int q = 0; q < 9; ++q) {
          float4 gv = gp4[q];
          g[4*q] = gv.x; g[4*q+1] = gv.y; g[4*q+2] = gv.z; g[4*q+3] = gv.w;
        }
        float t2r[9];
        #pragma unroll
        for (int j = 0; j < 9; ++j) t2r[j] = T2[a*9 + j];
        float4 yq  = *(const float4*)(Y + s0);
        float4 ylq = *(const float4*)(YL + s0);
        float yv[4]  = {yq.x, yq.y, yq.z, yq.w};
        float ylv[4] = {ylq.x, ylq.y, ylq.z, ylq.w};
        float yn4[4], ym4[4];
        #pragma unroll
        for (int d = 0; d < 4; ++d) {
          float re = 0.f;
          #pragma unroll
          for (int j = 0; j < 9; ++j) re = fmaf(g[d*9 + j], t2r[j], re);
          float w  = yv[d] + re;                         // MU = 1
          float yn = fmaxf(w - 0.005f, 0.f) - fmaxf(-w - 0.005f, 0.f);
          ym4[d] = fmaf(mom, yn - ylv[d], yn);
          yn4[d] = yn;
        }
        *(float4*)(YL + s0) = make_float4(yn4[0], yn4[1], yn4[2], yn4[3]);
        *(float4*)(Y  + s0) = make_float4(ym4[0], ym4[1], ym4[2], ym4[3]);
      }
      t = tn;
      __syncthreads();
    }
    // epilogue: YL holds y_final. Write plane + reflect-weighted bn_x stats.
    float wsum = 0.f, wss = 0.f;
    for (int s = tid; s < NS; s += 256) {
      float v = YL[s];
      ws_y[(bb*NS + s)*3 + ch] = v;
      int h = s / 72, w = s % 72;
      float wt = (float)((1 + (h == 1)) * (1 + (w == 1)));  // reflect-pad multiplicity
      wsum = fmaf(wt, v, wsum);
      wss  = fmaf(wt, v*v, wss);
    }
    __syncthreads();
    W1[tid] = wsum; T2[tid] = wss;
    __syncthreads();
    for (int off = 128; off > 0; off >>= 1) {
      if (tid < off) { W1[tid] += W1[tid + off]; T2[tid] += T2[tid + off]; }
      __syncthreads();
    }
    if (tid == 0) {
      atomicAdd(&bns[ch],     W1[0]);
      atomicAdd(&bns[3 + ch], T2[0]);
    }
  } else {
    // ------------------------- small paths (w, y, z) -------------------------
    float* TY  = smem;           // 5184
    float* Y7  = smem + 5184;    // 5184
    float* Z1  = smem;           // 6912  (reuses TY/Y7 space after y path)
    float* Z2  = smem + 6912;    // 1536
    float* ZU  = smem + 8448;    // 6912
    float* RED = smem + 15360;   // 512

    const float vwy10 = wy1[0], vwy11 = wy1[1], vwy12 = wy1[2], vby1 = by1[0];
    const float vww10 = ww1[0], vww11 = ww1[1], vww12 = ww1[2], vbw1 = bw1[0];
    for (int k = tid; k < NS; k += 256) {
      const float* xp = x + 3*k;
      float x0 = xp[0], x1 = xp[1], x2 = xp[2];
      out[5*k] = fmaxf(fmaf(x2, vww12, fmaf(x1, vww11, fmaf(x0, vww10, vbw1))), 0.f);
      TY[k]    = fmaxf(fmaf(x2, vwy12, fmaf(x1, vwy11, fmaf(x0, vwy10, vby1))), 0.f);
    }
    __syncthreads();
    // 7x7 SAME conv on (9,9), zero pad 3
    float ps = 0.f, pss = 0.f;
    const float vby7 = by7[0];
    for (int k = tid; k < NS; k += 256) {
      int bb = k / 81, p = k % 81, h = p / 9, w = p % 9;
      float acc = vby7;
      for (int kh = 0; kh < 7; ++kh) {
        int hh = h + kh - 3;
        if (hh < 0 || hh > 8) continue;
        for (int kw = 0; kw < 7; ++kw) {
          int wi = w + kw - 3;
          if (wi < 0 || wi > 8) continue;
          acc = fmaf(TY[bb*81 + hh*9 + wi], wy7[kh*7 + kw], acc);
        }
      }
      Y7[k] = acc;
      ps += acc; pss += acc*acc;
    }
    RED[tid] = ps; RED[256 + tid] = pss;
    __syncthreads();
    for (int off = 128; off > 0; off >>= 1) {
      if (tid < off) { RED[tid] += RED[tid + off]; RED[256 + tid] += RED[256 + tid + off]; }
      __syncthreads();
    }
    {
      float m  = RED[0]   * (1.f/5184.f);
      float v  = RED[256] * (1.f/5184.f) - m*m;
      float sc = bn_y_g[0] * rsqrtf(v + 1e-3f);
      float sh = bn_y_b[0] - m*sc;
      for (int k = tid; k < NS; k += 256) out[5*k + 3] = fmaf(Y7[k], sc, sh);
    }
    __syncthreads();
    // ---- z path ----  z1: 3x3 stride-3 conv (pad 0), bn, leaky 0.2
    if (tid < 128) RED[tid] = 0.f;
    for (int k = tid; k < 6912; k += 256) {
      int bb = k / 108, r = k % 108, u = r / 36, v3 = (r / 12) % 3, oc = r % 12;
      float acc = 0.f;
      #pragma unroll
      for (int kh = 0; kh < 3; ++kh)
        #pragma unroll
        for (int kw = 0; kw < 3; ++kw) {
          const float* xp = x + (bb*81 + (3*u + kh)*9 + (3*v3 + kw))*3;
          #pragma unroll
          for (int cc = 0; cc < 3; ++cc)
            acc = fmaf(xp[cc], wd1[((kh*3 + kw)*3 + cc)*12 + oc], acc);
        }
      Z1[k] = acc;
    }
    __syncthreads();
    for (int k = tid; k < 6912; k += 256) {
      float v = Z1[k]; int oc = k % 12;
      atomicAdd(&RED[oc], v); atomicAdd(&RED[64 + oc], v*v);
    }
    __syncthreads();
    for (int k = tid; k < 6912; k += 256) {
      int oc = k % 12;
      float m  = RED[oc] * (1.f/576.f);
      float v  = RED[64 + oc] * (1.f/576.f) - m*m;
      float sc = bnd1_g[oc] * rsqrtf(v + 1e-3f);
      float z  = fmaf(Z1[k] - m, sc, bnd1_b[oc]);
      Z1[k] = z >= 0.f ? z : 0.2f*z;
    }
    __syncthreads();
    if (tid < 128) RED[tid] = 0.f;
    for (int k = tid; k < 1536; k += 256) {      // z2: (3,3,12)->(1,1,24)
      int bb = k / 24, oc = k % 24;
      float acc = 0.f;
      for (int q = 0; q < 9; ++q)
        #pragma unroll
        for (int ic = 0; ic < 12; ++ic)
          acc = fmaf(Z1[bb*108 + q*12 + ic], wd2[(q*12 + ic)*24 + oc], acc);
      Z2[k] = acc;
    }
    __syncthreads();
    for (int k = tid; k < 1536; k += 256) {
      float v = Z2[k]; int oc = k % 24;
      atomicAdd(&RED[oc], v); atomicAdd(&RED[64 + oc], v*v);
    }
    __syncthreads();
    for (int k = tid; k < 1536; k += 256) {
      int oc = k % 24;
      float m  = RED[oc] * (1.f/64.f);
      float v  = RED[64 + oc] * (1.f/64.f) - m*m;
      float sc = bnd2_g[oc] * rsqrtf(v + 1e-3f);
      float z  = fmaf(Z2[k] - m, sc, bnd2_b[oc]);
      Z2[k] = z >= 0.f ? z : 0.2f*z;
    }
    __syncthreads();
    if (tid < 128) RED[tid] = 0.f;
    // convT(z2, wu1): out[y,x,o] = sum_i z2[i] * wu1[2-y,2-x,i,o]
    for (int k = tid; k < 6912; k += 256) {
      int bb = k / 108, r = k % 108, yy = r / 36, xx = (r / 12) % 3, o = r % 12;
      const float* wp = wu1 + ((2 - yy)*3 + (2 - xx))*288 + o;  // 288 = 24*12
      const float* zp = Z2 + bb*24;
      float acc = 0.f;
      #pragma unroll
      for (int i = 0; i < 24; ++i) acc = fmaf(zp[i], wp[i*12], acc);
      ZU[k] = acc;
    }
    __syncthreads();
    for (int k = tid; k < 6912; k += 256) {
      float v = ZU[k]; int o = k % 12;
      atomicAdd(&RED[o], v); atomicAdd(&RED[64 + o], v*v);
    }
    __syncthreads();
    for (int k = tid; k < 6912; k += 256) {
      int o = k % 12;
      float m  = RED[o] * (1.f/576.f);
      float v  = RED[64 + o] * (1.f/576.f) - m*m;
      float sc = bnu1_g[o] * rsqrtf(v + 1e-3f);
      float z  = fmaf(ZU[k] - m, sc, bnu1_b[o]);
      ZU[k] = fmaxf(z, 0.f);
    }
    __syncthreads();
    // final convT(concat([zu, z1]), wu2): i = y//3, ktap = 2 - y%3
    for (int k = tid; k < NS; k += 256) {
      int bb = k / 81, p = k % 81, h = p / 9, w = p % 9;
      int u = h / 3, v3 = w / 3, kh = 2 - (h % 3), kw = 2 - (w % 3);
      const float* wp = wu2 + (kh*3 + kw)*24;
      const float* zu = ZU + bb*108 + u*36 + v3*12;
      const float* z1 = Z1 + bb*108 + u*36 + v3*12;
      float acc = 0.f;
      #pragma unroll
      for (int i = 0; i < 12; ++i) acc = fmaf(zu[i], wp[i], acc);
      #pragma unroll
      for (int i = 0; i < 12; ++i) acc = fmaf(z1[i], wp[12 + i], acc);
      out[5*k + 4] = fmaxf(acc, 0.f);
    }
  }
}

// ---------------------------------------------------------------------------
// K2: per-image x path: fold bn_x into input, reflect-pad via |ph-1| indexing,
//     conv5x5 -> maxpool4(SAME) -> 1x1+relu -> maxpool2 -> out channels 1,2.
// ---------------------------------------------------------------------------
__global__ __launch_bounds__(512) void cs_xpath(
    const float* __restrict__ ws_y, const float* __restrict__ bns,
    const float* __restrict__ bn_x_g, const float* __restrict__ bn_x_b,
    const float* __restrict__ w5, const float* __restrict__ b5,
    const float* __restrict__ wx2, const float* __restrict__ bx2,
    float* __restrict__ out)
{
  __shared__ __align__(16) float xin[15552];   // 72*72*3, bn applied
  __shared__ float w5s[600];
  const int tid = threadIdx.x, bb = blockIdx.x;

  const float N = 64.f * 73.f * 73.f;
  float sc0, sc1, sc2, sh0, sh1, sh2;
  {
    float m0 = bns[0]/N, m1 = bns[1]/N, m2 = bns[2]/N;
    float v0 = bns[3]/N - m0*m0, v1 = bns[4]/N - m1*m1, v2 = bns[5]/N - m2*m2;
    sc0 = bn_x_g[0]*rsqrtf(v0 + 1e-3f); sh0 = bn_x_b[0] - m0*sc0;
    sc1 = bn_x_g[1]*rsqrtf(v1 + 1e-3f); sh1 = bn_x_b[1] - m1*sc1;
    sc2 = bn_x_g[2]*rsqrtf(v2 + 1e-3f); sh2 = bn_x_b[2] - m2*sc2;
  }
  for (int k = tid; k < 15552; k += 512) {
    int c = k - (k/3)*3;
    float sc = c == 0 ? sc0 : (c == 1 ? sc1 : sc2);
    float sh = c == 0 ? sh0 : (c == 1 ? sh1 : sh2);
    xin[k] = fmaf(ws_y[bb*15552 + k], sc, sh);
  }
  for (int k = tid; k < 600; k += 512) w5s[k] = w5[k];
  __syncthreads();

  float mx[8];
  const bool active = tid < 324;   // 18*18 pooled cells, one per thread
  if (active) {
    int p = tid / 18, q = tid % 18;
    #pragma unroll
    for (int o = 0; o < 8; ++o) mx[o] = -1e30f;
    int r0 = 4*p - 1; if (r0 < 0) r0 = 0;
    int r1 = 4*p + 2; if (r1 > 68) r1 = 68;
    int c0 = 4*q - 1; if (c0 < 0) c0 = 0;
    int c1 = 4*q + 2; if (c1 > 68) c1 = 68;
    for (int r = r0; r <= r1; ++r) {
      for (int cc = c0; cc <= c1; ++cc) {
        float acc[8];
        #pragma unroll
        for (int o = 0; o < 8; ++o) acc[o] = b5[o];
        #pragma unroll
        for (int kh = 0; kh < 5; ++kh) {
          int hs = r + kh - 1; hs = hs < 0 ? -hs : hs;   // reflect: |ph - 1|
          #pragma unroll
          for (int kw = 0; kw < 5; ++kw) {
            int wsc = cc + kw - 1; wsc = wsc < 0 ? -wsc : wsc;
            const float* xp = &xin[(hs*72 + wsc)*3];
            const float* wp = &w5s[(kh*5 + kw)*24];
            #pragma unroll
            for (int ci = 0; ci < 3; ++ci) {
              float xv = xp[ci];
              #pragma unroll
              for (int o = 0; o < 8; ++o) acc[o] = fmaf(xv, wp[ci*8 + o], acc[o]);
            }
          }
        }
        #pragma unroll
        for (int o = 0; o < 8; ++o) mx[o] = fmaxf(mx[o], acc[o]);
      }
    }
  }
  __syncthreads();            // all conv reads of xin done
  float* pool = xin;          // reuse LDS: [ (p*18+q)*8 + o ]
  if (active) {
    int p = tid / 18, q = tid % 18;
    #pragma unroll
    for (int o = 0; o < 8; ++o) pool[(p*18 + q)*8 + o] = mx[o];
  }
  __syncthreads();
  if (tid < 162) {            // 81 pixels x 2 out channels
    int u = tid & 1, pix = tid >> 1;
    int h = pix / 9, w = pix % 9;
    float m = -1e30f;
    #pragma unroll
    for (int dp = 0; dp < 2; ++dp)
      #pragma unroll
      for (int dq = 0; dq < 2; ++dq) {
        int p = 2*h + dp, q = 2*w + dq;
        float acc = bx2[u];
        #pragma unroll
        for (int o = 0; o < 8; ++o) acc = fmaf(pool[(p*18 + q)*8 + o], wx2[o*2 + u], acc);
        m = fmaxf(m, fmaxf(acc, 0.f));
      }
    out[(bb*81 + pix)*5 + 1 + u] = m;
  }
}

extern "C" void kernel_launch(void* const* d_in, const int* in_sizes, int n_in,
                              void* d_out, int out_size, void* d_ws, size_t ws_size,
                              hipStream_t stream) {
  (void)in_sizes; (void)n_in; (void)out_size; (void)ws_size;
  const float* x      = (const float*)d_in[0];
  const float* mat    = (const float*)d_in[1];
  const float* bn_x_g = (const float*)d_in[2];
  const float* bn_x_b = (const float*)d_in[3];
  const float* w5     = (const float*)d_in[4];
  const float* b5     = (const float*)d_in[5];
  const float* wx2    = (const float*)d_in[6];
  const float* bx2    = (const float*)d_in[7];
  const float* wy1    = (const float*)d_in[8];
  const float* by1    = (const float*)d_in[9];
  const float* wy7    = (const float*)d_in[10];
  const float* by7    = (const float*)d_in[11];
  const float* bn_y_g = (const float*)d_in[12];
  const float* bn_y_b = (const float*)d_in[13];
  const float* ww1    = (const float*)d_in[14];
  const float* bw1    = (const float*)d_in[15];
  const float* wd1    = (const float*)d_in[16];
  const float* bnd1_g = (const float*)d_in[17];
  const float* bnd1_b = (const float*)d_in[18];
  const float* wd2    = (const float*)d_in[19];
  const float* bnd2_g = (const float*)d_in[20];
  const float* bnd2_b = (const float*)d_in[21];
  const float* wu1    = (const float*)d_in[22];
  const float* bnu1_g = (const float*)d_in[23];
  const float* bnu1_b = (const float*)d_in[24];
  const float* wu2    = (const float*)d_in[25];

  float* outp = (float*)d_out;
  float* ws_y = (float*)d_ws;                 // 64*5184*3 floats
  float* bns  = ws_y + 64*5184*3;             // 6 floats: sum[3], sumsq[3]

  hipMemsetAsync(bns, 0, 6*sizeof(float), stream);
  cs_fista_small<<<dim3(193), dim3(256), 0, stream>>>(
      x, mat, wy1, by1, wy7, by7, bn_y_g, bn_y_b, ww1, bw1,
      wd1, bnd1_g, bnd1_b, wd2, bnd2_g, bnd2_b, wu1, bnu1_g, bnu1_b, wu2,
      ws_y, bns, outp);
  cs_xpath<<<dim3(64), dim3(512), 0, stream>>>(
      ws_y, bns, bn_x_g, bn_x_b, w5, b5, wx2, bx2, outp);
}

// Round 3
// 452.353 us; speedup vs baseline: 2.1883x; 2.1883x over previous
//
#include <hip/hip_runtime.h>
#include <hip/hip_bf16.h>
#include <math.h>

#define NS 5184   // 72*72

// ---------------------------------------------------------------------------
// K1 (512 thr): blocks 0..191 = FISTA (one (batch,channel) chain per block,
//     all in LDS, exact separable structure mat = gp (x) gp).
//     block 192 = small paths (w, y, z) independent of FISTA.
// ws_y layout: PLANAR [b][c][5184] (coalesced full-line writes & reads).
// ---------------------------------------------------------------------------
__global__ __launch_bounds__(512) void cs_fista_small(
    const float* __restrict__ x, const float* __restrict__ mat,
    const float* __restrict__ wy1, const float* __restrict__ by1,
    const float* __restrict__ wy7, const float* __restrict__ by7,
    const float* __restrict__ bn_y_g, const float* __restrict__ bn_y_b,
    const float* __restrict__ ww1, const float* __restrict__ bw1,
    const float* __restrict__ wd1, const float* __restrict__ bnd1_g, const float* __restrict__ bnd1_b,
    const float* __restrict__ wd2, const float* __restrict__ bnd2_g, const float* __restrict__ bnd2_b,
    const float* __restrict__ wu1, const float* __restrict__ bnu1_g, const float* __restrict__ bnu1_b,
    const float* __restrict__ wu2,
    float* __restrict__ ws_y, float* __restrict__ bns, float* __restrict__ out)
{
  __shared__ __align__(16) float smem[16384];   // 64 KB exactly
  const int tid = threadIdx.x;
  const int blk = blockIdx.x;

  if (blk < 192) {
    // ------------------------- FISTA -------------------------
    const int bb = blk / 3, ch = blk % 3;
    float* Y   = smem;           // 5184  y_tmp (momentum state)
    float* YL  = smem + 5184;    // 5184  y_new of prev iter
    float* W1T = smem + 10368;   // 648   [j*72+a] = sum_b Y[a,b] gp[b,j]
    float* T2  = smem + 11016;   // 648   [a*9+j]
    float* GP  = smem + 11664;   // 648   gp[b*9+j]
    float* GPT = smem + 12312;   // 648   gp transposed [j*72+b]
    float* Rm  = smem + 12960;   // 81
    float* IM  = smem + 13044;   // 81

    for (int k = tid; k < 648; k += 512) {
      int a = k / 9, i = k % 9;
      // mat[(a,a),(i,i)] = gp[a,i]^2 exactly (Kronecker structure, gp > 0)
      float v = sqrtf(mat[a*73*81 + i*10]);
      GP[k] = v;
      GPT[i*72 + a] = v;
    }
    for (int k = tid; k < NS; k += 512) { Y[k] = 0.f; YL[k] = 0.f; }
    if (tid < 81) IM[tid] = x[(bb*81 + tid)*3 + ch];
    __syncthreads();

    float t = 1.f;
    for (int it = 0; it < 100; ++it) {
      // stage 1: W1T[j*72+a] = sum_b Y[a,b] * gp[b,j]  (float4 dots)
      for (int k = tid; k < 648; k += 512) {
        int a = k / 9, j = k % 9;
        const float4* yr = (const float4*)(Y + a*72);
        const float4* gr = (const float4*)(GPT + j*72);
        float acc = 0.f;
        #pragma unroll
        for (int q = 0; q < 18; ++q) {
          float4 yv = yr[q], gv = gr[q];
          acc = fmaf(yv.x, gv.x, acc);
          acc = fmaf(yv.y, gv.y, acc);
          acc = fmaf(yv.z, gv.z, acc);
          acc = fmaf(yv.w, gv.w, acc);
        }
        W1T[j*72 + a] = acc;
      }
      __syncthreads();
      // stage 2: Rm[i,j] = IM[i,j] - sum_a gp[a,i] * W1[a,j]  (float4 dots)
      if (tid < 81) {
        int i = tid / 9, j = tid % 9;
        const float4* gr = (const float4*)(GPT + i*72);
        const float4* wr = (const float4*)(W1T + j*72);
        float acc = 0.f;
        #pragma unroll
        for (int q = 0; q < 18; ++q) {
          float4 gv = gr[q], wv = wr[q];
          acc = fmaf(gv.x, wv.x, acc);
          acc = fmaf(gv.y, wv.y, acc);
          acc = fmaf(gv.z, wv.z, acc);
          acc = fmaf(gv.w, wv.w, acc);
        }
        Rm[tid] = IM[tid] - acc;
      }
      __syncthreads();
      // stage 3: T2[a,j] = sum_i gp[a,i] * Rm[i,j]
      for (int k = tid; k < 648; k += 512) {
        int a = k / 9, j = k % 9;
        float acc = 0.f;
        #pragma unroll
        for (int i = 0; i < 9; ++i) acc = fmaf(GP[a*9 + i], Rm[i*9 + j], acc);
        T2[k] = acc;
      }
      __syncthreads();
      // stage 4: re[a,b] = sum_j gp[b,j] T2[a,j]; soft-threshold + momentum.
      const float tn  = 0.5f * (1.f + sqrtf(1.f + 4.f*t*t));
      const float mom = (t - 1.f) / tn;
      for (int k = tid; k < 1296; k += 512) {   // quads of 4 consecutive s
        const int s0 = 4*k;
        const int a = s0 / 72, b = s0 % 72;     // b % 4 == 0 -> 16B aligned gp rows
        float g[36];
        const float4* gp4 = (const float4*)(GP + b*9);
        #pragma unroll
        for (int q = 0; q < 9; ++q) {
          float4 gv = gp4[q];
          g[4*q] = gv.x; g[4*q+1] = gv.y; g[4*q+2] = gv.z; g[4*q+3] = gv.w;
        }
        float t2r[9];
        #pragma unroll
        for (int j = 0; j < 9; ++j) t2r[j] = T2[a*9 + j];
        float4 yq  = *(const float4*)(Y + s0);
        float4 ylq = *(const float4*)(YL + s0);
        float yv[4]  = {yq.x, yq.y, yq.z, yq.w};
        float ylv[4] = {ylq.x, ylq.y, ylq.z, ylq.w};
        float yn4[4], ym4[4];
        #pragma unroll
        for (int d = 0; d < 4; ++d) {
          float re = 0.f;
          #pragma unroll
          for (int j = 0; j < 9; ++j) re = fmaf(g[d*9 + j], t2r[j], re);
          float w  = yv[d] + re;                         // MU = 1
          float yn = fmaxf(w - 0.005f, 0.f) - fmaxf(-w - 0.005f, 0.f);
          ym4[d] = fmaf(mom, yn - ylv[d], yn);
          yn4[d] = yn;
        }
        *(float4*)(YL + s0) = make_float4(yn4[0], yn4[1], yn4[2], yn4[3]);
        *(float4*)(Y  + s0) = make_float4(ym4[0], ym4[1], ym4[2], ym4[3]);
      }
      t = tn;
      __syncthreads();
    }
    // epilogue: YL holds y_final. Planar coalesced write + reflect-weighted stats.
    float* wp = ws_y + (bb*3 + ch)*NS;
    float wsum = 0.f, wss = 0.f;
    for (int s = tid; s < NS; s += 512) {
      float v = YL[s];
      wp[s] = v;
      int h = s / 72, w = s % 72;
      float wt = (float)((1 + (h == 1)) * (1 + (w == 1)));  // reflect-pad multiplicity
      wsum = fmaf(wt, v, wsum);
      wss  = fmaf(wt, v*v, wss);
    }
    __syncthreads();                 // Y/YL reads done; reuse Y region as scratch
    float* RA = smem;                // 512
    float* RB = smem + 512;          // 512
    RA[tid] = wsum; RB[tid] = wss;
    __syncthreads();
    for (int off = 256; off > 0; off >>= 1) {
      if (tid < off) { RA[tid] += RA[tid + off]; RB[tid] += RB[tid + off]; }
      __syncthreads();
    }
    if (tid == 0) {
      atomicAdd(&bns[ch],     RA[0]);
      atomicAdd(&bns[3 + ch], RB[0]);
    }
  } else {
    // ------------------------- small paths (w, y, z) -------------------------
    float* TY  = smem;           // 5184
    float* Y7  = smem + 5184;    // 5184
    float* Z1  = smem;           // 6912  (reuses TY/Y7 after y path)
    float* Z2  = smem + 6912;    // 1536
    float* ZU  = smem + 8448;    // 6912
    float* RED = smem + 15360;   // 1024

    const float vwy10 = wy1[0], vwy11 = wy1[1], vwy12 = wy1[2], vby1 = by1[0];
    const float vww10 = ww1[0], vww11 = ww1[1], vww12 = ww1[2], vbw1 = bw1[0];
    for (int k = tid; k < NS; k += 512) {
      const float* xp = x + 3*k;
      float x0 = xp[0], x1 = xp[1], x2 = xp[2];
      out[5*k] = fmaxf(fmaf(x2, vww12, fmaf(x1, vww11, fmaf(x0, vww10, vbw1))), 0.f);
      TY[k]    = fmaxf(fmaf(x2, vwy12, fmaf(x1, vwy11, fmaf(x0, vwy10, vby1))), 0.f);
    }
    __syncthreads();
    // 7x7 SAME conv on (9,9), zero pad 3
    float ps = 0.f, pss = 0.f;
    const float vby7 = by7[0];
    for (int k = tid; k < NS; k += 512) {
      int bb = k / 81, p = k % 81, h = p / 9, w = p % 9;
      float acc = vby7;
      for (int kh = 0; kh < 7; ++kh) {
        int hh = h + kh - 3;
        if (hh < 0 || hh > 8) continue;
        for (int kw = 0; kw < 7; ++kw) {
          int wi = w + kw - 3;
          if (wi < 0 || wi > 8) continue;
          acc = fmaf(TY[bb*81 + hh*9 + wi], wy7[kh*7 + kw], acc);
        }
      }
      Y7[k] = acc;
      ps += acc; pss += acc*acc;
    }
    RED[tid] = ps; RED[512 + tid] = pss;
    __syncthreads();
    for (int off = 256; off > 0; off >>= 1) {
      if (tid < off) { RED[tid] += RED[tid + off]; RED[512 + tid] += RED[512 + tid + off]; }
      __syncthreads();
    }
    {
      float m  = RED[0]   * (1.f/5184.f);
      float v  = RED[512] * (1.f/5184.f) - m*m;
      float sc = bn_y_g[0] * rsqrtf(v + 1e-3f);
      float sh = bn_y_b[0] - m*sc;
      for (int k = tid; k < NS; k += 512) out[5*k + 3] = fmaf(Y7[k], sc, sh);
    }
    __syncthreads();
    // ---- z path ----  z1: 3x3 stride-3 conv (pad 0), bn, leaky 0.2
    if (tid < 128) RED[tid] = 0.f;
    __syncthreads();
    for (int k = tid; k < 6912; k += 512) {
      int bb = k / 108, r = k % 108, u = r / 36, v3 = (r / 12) % 3, oc = r % 12;
      float acc = 0.f;
      #pragma unroll
      for (int kh = 0; kh < 3; ++kh)
        #pragma unroll
        for (int kw = 0; kw < 3; ++kw) {
          const float* xp = x + (bb*81 + (3*u + kh)*9 + (3*v3 + kw))*3;
          #pragma unroll
          for (int cc = 0; cc < 3; ++cc)
            acc = fmaf(xp[cc], wd1[((kh*3 + kw)*3 + cc)*12 + oc], acc);
        }
      Z1[k] = acc;
    }
    __syncthreads();
    for (int k = tid; k < 6912; k += 512) {
      float v = Z1[k]; int oc = k % 12;
      atomicAdd(&RED[oc], v); atomicAdd(&RED[64 + oc], v*v);
    }
    __syncthreads();
    for (int k = tid; k < 6912; k += 512) {
      int oc = k % 12;
      float m  = RED[oc] * (1.f/576.f);
      float v  = RED[64 + oc] * (1.f/576.f) - m*m;
      float sc = bnd1_g[oc] * rsqrtf(v + 1e-3f);
      float z  = fmaf(Z1[k] - m, sc, bnd1_b[oc]);
      Z1[k] = z >= 0.f ? z : 0.2f*z;
    }
    __syncthreads();
    if (tid < 128) RED[tid] = 0.f;
    __syncthreads();
    for (int k = tid; k < 1536; k += 512) {      // z2: (3,3,12)->(1,1,24)
      int bb = k / 24, oc = k % 24;
      float acc = 0.f;
      for (int q = 0; q < 9; ++q)
        #pragma unroll
        for (int ic = 0; ic < 12; ++ic)
          acc = fmaf(Z1[bb*108 + q*12 + ic], wd2[(q*12 + ic)*24 + oc], acc);
      Z2[k] = acc;
    }
    __syncthreads();
    for (int k = tid; k < 1536; k += 512) {
      float v = Z2[k]; int oc = k % 24;
      atomicAdd(&RED[oc], v); atomicAdd(&RED[64 + oc], v*v);
    }
    __syncthreads();
    for (int k = tid; k < 1536; k += 512) {
      int oc = k % 24;
      float m  = RED[oc] * (1.f/64.f);
      float v  = RED[64 + oc] * (1.f/64.f) - m*m;
      float sc = bnd2_g[oc] * rsqrtf(v + 1e-3f);
      float z  = fmaf(Z2[k] - m, sc, bnd2_b[oc]);
      Z2[k] = z >= 0.f ? z : 0.2f*z;
    }
    __syncthreads();
    if (tid < 128) RED[tid] = 0.f;
    __syncthreads();
    // convT(z2, wu1): out[y,x,o] = sum_i z2[i] * wu1[2-y,2-x,i,o]
    for (int k = tid; k < 6912; k += 512) {
      int bb = k / 108, r = k % 108, yy = r / 36, xx = (r / 12) % 3, o = r % 12;
      const float* wp = wu1 + ((2 - yy)*3 + (2 - xx))*288 + o;  // 288 = 24*12
      const float* zp = Z2 + bb*24;
      float acc = 0.f;
      #pragma unroll
      for (int i = 0; i < 24; ++i) acc = fmaf(zp[i], wp[i*12], acc);
      ZU[k] = acc;
    }
    __syncthreads();
    for (int k = tid; k < 6912; k += 512) {
      float v = ZU[k]; int o = k % 12;
      atomicAdd(&RED[o], v); atomicAdd(&RED[64 + o], v*v);
    }
    __syncthreads();
    for (int k = tid; k < 6912; k += 512) {
      int o = k % 12;
      float m  = RED[o] * (1.f/576.f);
      float v  = RED[64 + o] * (1.f/576.f) - m*m;
      float sc = bnu1_g[o] * rsqrtf(v + 1e-3f);
      float z  = fmaf(ZU[k] - m, sc, bnu1_b[o]);
      ZU[k] = fmaxf(z, 0.f);
    }
    __syncthreads();
    // final convT(concat([zu, z1]), wu2)
    for (int k = tid; k < NS; k += 512) {
      int bb = k / 81, p = k % 81, h = p / 9, w = p % 9;
      int u = h / 3, v3 = w / 3, kh = 2 - (h % 3), kw = 2 - (w % 3);
      const float* wpp = wu2 + (kh*3 + kw)*24;
      const float* zu = ZU + bb*108 + u*36 + v3*12;
      const float* z1 = Z1 + bb*108 + u*36 + v3*12;
      float acc = 0.f;
      #pragma unroll
      for (int i = 0; i < 12; ++i) acc = fmaf(zu[i], wpp[i], acc);
      #pragma unroll
      for (int i = 0; i < 12; ++i) acc = fmaf(z1[i], wpp[12 + i], acc);
      out[5*k + 4] = fmaxf(acc, 0.f);
    }
  }
}

// ---------------------------------------------------------------------------
// K2 (384 thr): per-image x path. Planar LDS xin (row stride 73), rolled
// 5x5 tap loops, register-preloaded biases. conv5x5(reflect) -> maxpool4
// (SAME) -> 1x1+relu -> maxpool2 -> out channels 1,2.
// ---------------------------------------------------------------------------
__global__ __launch_bounds__(384) void cs_xpath(
    const float* __restrict__ ws_y, const float* __restrict__ bns,
    const float* __restrict__ bn_x_g, const float* __restrict__ bn_x_b,
    const float* __restrict__ w5, const float* __restrict__ b5,
    const float* __restrict__ wx2, const float* __restrict__ bx2,
    float* __restrict__ out)
{
  __shared__ __align__(16) float xin[3*5256 + 600];   // 3 planes (72 rows x stride 73) + w5s
  float* w5s = xin + 3*5256;
  const int tid = threadIdx.x, bb = blockIdx.x;

  const float N = 64.f * 73.f * 73.f;
  float sc[3], sh[3];
  #pragma unroll
  for (int c = 0; c < 3; ++c) {
    float m = bns[c]/N;
    float v = bns[3 + c]/N - m*m;
    sc[c] = bn_x_g[c]*rsqrtf(v + 1e-3f);
    sh[c] = bn_x_b[c] - m*sc[c];
  }
  #pragma unroll
  for (int c = 0; c < 3; ++c) {
    const float* src = ws_y + (bb*3 + c)*NS;
    float* dst = xin + c*5256;
    float s1 = sc[c], s2 = sh[c];
    for (int k = tid; k < NS; k += 384) {
      int h = k / 72, w = k - h*72;
      dst[h*73 + w] = fmaf(src[k], s1, s2);
    }
  }
  for (int k = tid; k < 600; k += 384) w5s[k] = w5[k];
  float b5r[8];
  #pragma unroll
  for (int o = 0; o < 8; ++o) b5r[o] = b5[o];
  __syncthreads();

  float mx[8];
  const bool active = tid < 324;   // 18*18 pooled cells, one per thread
  if (active) {
    int p = tid / 18, q = tid % 18;
    #pragma unroll
    for (int o = 0; o < 8; ++o) mx[o] = -1e30f;
    int r0 = 4*p - 1; if (r0 < 0) r0 = 0;
    int r1 = 4*p + 2; if (r1 > 68) r1 = 68;
    int c0 = 4*q - 1; if (c0 < 0) c0 = 0;
    int c1 = 4*q + 2; if (c1 > 68) c1 = 68;
    for (int r = r0; r <= r1; ++r) {
      for (int cc = c0; cc <= c1; ++cc) {
        float acc[8];
        #pragma unroll
        for (int o = 0; o < 8; ++o) acc[o] = b5r[o];
        #pragma unroll 1
        for (int kh = 0; kh < 5; ++kh) {
          int hs = r + kh - 1; hs = hs < 0 ? -hs : hs;   // reflect: |ph - 1|
          int rowb = hs*73;
          #pragma unroll 1
          for (int kw = 0; kw < 5; ++kw) {
            int wsc = cc + kw - 1; wsc = wsc < 0 ? -wsc : wsc;
            const float* wp = &w5s[(kh*5 + kw)*24];
            int a = rowb + wsc;
            float x0 = xin[a], x1 = xin[5256 + a], x2 = xin[2*5256 + a];
            #pragma unroll
            for (int o = 0; o < 8; ++o) {
              float t = fmaf(x0, wp[o], acc[o]);
              t = fmaf(x1, wp[8 + o], t);
              acc[o] = fmaf(x2, wp[16 + o], t);
            }
          }
        }
        #pragma unroll
        for (int o = 0; o < 8; ++o) mx[o] = fmaxf(mx[o], acc[o]);
      }
    }
  }
  __syncthreads();            // all conv reads of xin done
  float* pool = xin;          // reuse LDS: [ (p*18+q)*8 + o ]
  if (active) {
    int p = tid / 18, q = tid % 18;
    #pragma unroll
    for (int o = 0; o < 8; ++o) pool[(p*18 + q)*8 + o] = mx[o];
  }
  __syncthreads();
  if (tid < 162) {            // 81 pixels x 2 out channels
    int u = tid & 1, pix = tid >> 1;
    int h = pix / 9, w = pix % 9;
    float m = -1e30f;
    #pragma unroll
    for (int dp = 0; dp < 2; ++dp)
      #pragma unroll
      for (int dq = 0; dq < 2; ++dq) {
        int p = 2*h + dp, q = 2*w + dq;
        float acc = bx2[u];
        #pragma unroll
        for (int o = 0; o < 8; ++o) acc = fmaf(pool[(p*18 + q)*8 + o], wx2[o*2 + u], acc);
        m = fmaxf(m, fmaxf(acc, 0.f));
      }
    out[(bb*81 + pix)*5 + 1 + u] = m;
  }
}

extern "C" void kernel_launch(void* const* d_in, const int* in_sizes, int n_in,
                              void* d_out, int out_size, void* d_ws, size_t ws_size,
                              hipStream_t stream) {
  (void)in_sizes; (void)n_in; (void)out_size; (void)ws_size;
  const float* x      = (const float*)d_in[0];
  const float* mat    = (const float*)d_in[1];
  const float* bn_x_g = (const float*)d_in[2];
  const float* bn_x_b = (const float*)d_in[3];
  const float* w5     = (const float*)d_in[4];
  const float* b5     = (const float*)d_in[5];
  const float* wx2    = (const float*)d_in[6];
  const float* bx2    = (const float*)d_in[7];
  const float* wy1    = (const float*)d_in[8];
  const float* by1    = (const float*)d_in[9];
  const float* wy7    = (const float*)d_in[10];
  const float* by7    = (const float*)d_in[11];
  const float* bn_y_g = (const float*)d_in[12];
  const float* bn_y_b = (const float*)d_in[13];
  const float* ww1    = (const float*)d_in[14];
  const float* bw1    = (const float*)d_in[15];
  const float* wd1    = (const float*)d_in[16];
  const float* bnd1_g = (const float*)d_in[17];
  const float* bnd1_b = (const float*)d_in[18];
  const float* wd2    = (const float*)d_in[19];
  const float* bnd2_g = (const float*)d_in[20];
  const float* bnd2_b = (const float*)d_in[21];
  const float* wu1    = (const float*)d_in[22];
  const float* bnu1_g = (const float*)d_in[23];
  const float* bnu1_b = (const float*)d_in[24];
  const float* wu2    = (const float*)d_in[25];

  float* outp = (float*)d_out;
  float* ws_y = (float*)d_ws;                 // planar: 64*3*5184 floats
  float* bns  = ws_y + 64*3*5184;             // 6 floats: sum[3], sumsq[3]

  hipMemsetAsync(bns, 0, 6*sizeof(float), stream);
  cs_fista_small<<<dim3(193), dim3(512), 0, stream>>>(
      x, mat, wy1, by1, wy7, by7, bn_y_g, bn_y_b, ww1, bw1,
      wd1, bnd1_g, bnd1_b, wd2, bnd2_g, bnd2_b, wu1, bnu1_g, bnu1_b, wu2,
      ws_y, bns, outp);
  cs_xpath<<<dim3(64), dim3(384), 0, stream>>>(
      ws_y, bns, bn_x_g, bn_x_b, w5, b5, wx2, bx2, outp);
}

// Round 5
// 425.843 us; speedup vs baseline: 2.3245x; 1.0623x over previous
//
#include <hip/hip_runtime.h>
#include <hip/hip_bf16.h>
#include <math.h>

#define NS 5184   // 72*72

// ---------------------------------------------------------------------------
// K1 (512 thr): blocks 0..191 = FISTA, one (batch,channel) chain per block.
// Separable mat = gp (x) gp. 3 uniform stages/iter, 3 barriers:
//   S1: W1T[j][a] = sum_b Y[a,b] gp[b,j]            (648 items, dot-72)
//   S2: T2[a][j]  = GIM[a][j] - sum_b A[a,b] W1[b,j] (648 items, dot-72)
//       where A = gp gp^T (72x72 const), GIM = gp*IM (const)
//   S3: re[a,b] = sum_j T2[a,j] gp[b,j]; soft-thresh + momentum (1296 quads)
// y_tmp/y_last quads live in REGISTERS (fixed thread<->quad map).
// block 192 = small paths (w, y, z) independent of FISTA.
// ---------------------------------------------------------------------------
__global__ __launch_bounds__(512) void cs_fista_small(
    const float* __restrict__ x, const float* __restrict__ mat,
    const float* __restrict__ wy1, const float* __restrict__ by1,
    const float* __restrict__ wy7, const float* __restrict__ by7,
    const float* __restrict__ bn_y_g, const float* __restrict__ bn_y_b,
    const float* __restrict__ ww1, const float* __restrict__ bw1,
    const float* __restrict__ wd1, const float* __restrict__ bnd1_g, const float* __restrict__ bnd1_b,
    const float* __restrict__ wd2, const float* __restrict__ bnd2_g, const float* __restrict__ bnd2_b,
    const float* __restrict__ wu1, const float* __restrict__ bnu1_g, const float* __restrict__ bnu1_b,
    const float* __restrict__ wu2,
    float* __restrict__ ws_y, float* __restrict__ bns, float* __restrict__ out)
{
  __shared__ __align__(16) float smem[16384];   // 64 KB
  const int tid = threadIdx.x;
  const int blk = blockIdx.x;

  if (blk < 192) {
    // ------------------------- FISTA -------------------------
    const int bb = blk / 3, ch = blk % 3;
    float* Y   = smem;            // 5184  y_mom (LDS copy for S1)
    float* A   = smem + 5184;     // 5184  gp gp^T
    float* GT  = smem + 10368;    // 9*76  GT[j][b] = gp[b][j]  (pad 76)
    float* W1T = smem + 11052;    // 9*76  W1T[j][a]            (pad 76)
    float* T2  = smem + 11736;    // 72*12                       (pad 12)
    float* GIM = smem + 12600;    // 72*12                       (pad 12)
    float* IM  = smem + 13464;    // 81
    float* GP  = smem + 13548;    // 72*9 (setup only)
    float* RED = smem + 14196;    // 1024 (epilogue reduction)

    // ---- setup ----
    for (int k = tid; k < 648; k += 512) {
      int a = k / 9, i = k % 9;
      // mat[(a,a),(i,i)] = gp[a,i]^2 exactly (Kronecker structure, gp > 0)
      float v = sqrtf(mat[a*73*81 + i*10]);
      GP[k] = v;
      GT[i*76 + a] = v;
    }
    if (tid < 81) IM[tid] = x[(bb*81 + tid)*3 + ch];
    for (int k = tid; k < NS; k += 512) Y[k] = 0.f;
    __syncthreads();
    for (int k = tid; k < NS; k += 512) {        // A = GP GP^T
      int a = k / 72, b = k - (k/72)*72;
      const float* ga = GP + a*9;
      const float* gb = GP + b*9;
      float acc = 0.f;
      #pragma unroll
      for (int i = 0; i < 9; ++i) acc = fmaf(ga[i], gb[i], acc);
      A[k] = acc;
    }
    for (int k = tid; k < 648; k += 512) {       // GIM = GP * IM
      int a = k / 9, j = k % 9;
      const float* ga = GP + a*9;
      float acc = 0.f;
      #pragma unroll
      for (int i = 0; i < 9; ++i) acc = fmaf(ga[i], IM[i*9 + j], acc);
      GIM[a*12 + j] = acc;
    }
    float yr_[3][4], yl_[3][4];                  // y_mom / y_last quads in regs
    #pragma unroll
    for (int q = 0; q < 3; ++q)
      #pragma unroll
      for (int d = 0; d < 4; ++d) { yr_[q][d] = 0.f; yl_[q][d] = 0.f; }
    __syncthreads();

    float t = 1.f;
    for (int it = 0; it < 100; ++it) {
      // ---- S1: W1T[j][a] = dot72(Y row a, GT row j) ----
      #pragma unroll
      for (int rep = 0; rep < 2; ++rep) {
        int k = tid + rep*512;
        if (k < 648) {
          int a = k / 9, j = k % 9;
          const float4* yr = (const float4*)(Y + a*72);
          const float4* gr = (const float4*)(GT + j*76);
          float p0=0,p1=0,p2=0,p3=0,p4=0,p5=0,p6=0,p7=0;
          #pragma unroll
          for (int q = 0; q < 18; q += 2) {
            float4 y0 = yr[q],   g0 = gr[q];
            float4 y1 = yr[q+1], g1 = gr[q+1];
            p0 = fmaf(y0.x, g0.x, p0); p1 = fmaf(y0.y, g0.y, p1);
            p2 = fmaf(y0.z, g0.z, p2); p3 = fmaf(y0.w, g0.w, p3);
            p4 = fmaf(y1.x, g1.x, p4); p5 = fmaf(y1.y, g1.y, p5);
            p6 = fmaf(y1.z, g1.z, p6); p7 = fmaf(y1.w, g1.w, p7);
          }
          W1T[j*76 + a] = ((p0+p1)+(p2+p3)) + ((p4+p5)+(p6+p7));
        }
      }
      __syncthreads();
      // ---- S2: T2[a][j] = GIM[a][j] - dot72(A row a, W1T row j) ----
      #pragma unroll
      for (int rep = 0; rep < 2; ++rep) {
        int k = tid + rep*512;
        if (k < 648) {
          int a = k / 9, j = k % 9;
          const float4* ar = (const float4*)(A + a*72);
          const float4* wr = (const float4*)(W1T + j*76);
          float p0=0,p1=0,p2=0,p3=0,p4=0,p5=0,p6=0,p7=0;
          #pragma unroll
          for (int q = 0; q < 18; q += 2) {
            float4 a0 = ar[q],   w0 = wr[q];
            float4 a1 = ar[q+1], w1 = wr[q+1];
            p0 = fmaf(a0.x, w0.x, p0); p1 = fmaf(a0.y, w0.y, p1);
            p2 = fmaf(a0.z, w0.z, p2); p3 = fmaf(a0.w, w0.w, p3);
            p4 = fmaf(a1.x, w1.x, p4); p5 = fmaf(a1.y, w1.y, p5);
            p6 = fmaf(a1.z, w1.z, p6); p7 = fmaf(a1.w, w1.w, p7);
          }
          T2[a*12 + j] = GIM[a*12 + j] - (((p0+p1)+(p2+p3)) + ((p4+p5)+(p6+p7)));
        }
      }
      __syncthreads();
      // ---- S3: re + soft-threshold + momentum, quads in registers ----
      const float tn  = 0.5f * (1.f + sqrtf(1.f + 4.f*t*t));
      const float mom = (t - 1.f) / tn;
      #pragma unroll
      for (int qi = 0; qi < 3; ++qi) {
        int k = tid + qi*512;
        if (k < 1296) {
          int s0 = 4*k;
          int a = s0 / 72, b = s0 - a*72;        // b % 4 == 0
          float t2r[9];
          #pragma unroll
          for (int j = 0; j < 9; ++j) t2r[j] = T2[a*12 + j];
          float re[4] = {0.f, 0.f, 0.f, 0.f};
          #pragma unroll
          for (int j = 0; j < 9; ++j) {
            float4 gv = *(const float4*)(GT + j*76 + b);
            re[0] = fmaf(gv.x, t2r[j], re[0]);
            re[1] = fmaf(gv.y, t2r[j], re[1]);
            re[2] = fmaf(gv.z, t2r[j], re[2]);
            re[3] = fmaf(gv.w, t2r[j], re[3]);
          }
          float ym[4];
          #pragma unroll
          for (int d = 0; d < 4; ++d) {
            float w  = yr_[qi][d] + re[d];       // MU = 1
            float yn = fmaxf(w - 0.005f, 0.f) - fmaxf(-w - 0.005f, 0.f);
            ym[d] = fmaf(mom, yn - yl_[qi][d], yn);
            yl_[qi][d] = yn;
            yr_[qi][d] = ym[d];
          }
          *(float4*)(Y + s0) = make_float4(ym[0], ym[1], ym[2], ym[3]);
        }
      }
      t = tn;
      __syncthreads();
    }
    // ---- epilogue: yl_ holds y_final; write planar + reflect-weighted stats ----
    float* wp = ws_y + (bb*3 + ch)*NS;
    float wsum = 0.f, wss = 0.f;
    #pragma unroll
    for (int qi = 0; qi < 3; ++qi) {
      int k = tid + qi*512;
      if (k < 1296) {
        int s0 = 4*k;
        *(float4*)(wp + s0) = make_float4(yl_[qi][0], yl_[qi][1], yl_[qi][2], yl_[qi][3]);
        int h = s0 / 72, w0 = s0 - (s0/72)*72;
        #pragma unroll
        for (int d = 0; d < 4; ++d) {
          float wt = (float)((1 + (h == 1)) * (1 + (w0 + d == 1)));  // reflect multiplicity
          wsum = fmaf(wt, yl_[qi][d], wsum);
          wss  = fmaf(wt * yl_[qi][d], yl_[qi][d], wss);
        }
      }
    }
    RED[tid] = wsum; RED[512 + tid] = wss;
    __syncthreads();
    for (int off = 256; off > 0; off >>= 1) {
      if (tid < off) { RED[tid] += RED[tid + off]; RED[512 + tid] += RED[512 + tid + off]; }
      __syncthreads();
    }
    if (tid == 0) {
      atomicAdd(&bns[ch],     RED[0]);
      atomicAdd(&bns[3 + ch], RED[512]);
    }
  } else {
    // ------------------------- small paths (w, y, z) -------------------------
    float* TY  = smem;           // 5184
    float* Y7  = smem + 5184;    // 5184
    float* Z1  = smem;           // 6912  (reuses TY/Y7 after y path)
    float* Z2  = smem + 6912;    // 1536
    float* ZU  = smem + 8448;    // 6912
    float* RED = smem + 15360;   // 1024

    const float vwy10 = wy1[0], vwy11 = wy1[1], vwy12 = wy1[2], vby1 = by1[0];
    const float vww10 = ww1[0], vww11 = ww1[1], vww12 = ww1[2], vbw1 = bw1[0];
    for (int k = tid; k < NS; k += 512) {
      const float* xp = x + 3*k;
      float x0 = xp[0], x1 = xp[1], x2 = xp[2];
      out[5*k] = fmaxf(fmaf(x2, vww12, fmaf(x1, vww11, fmaf(x0, vww10, vbw1))), 0.f);
      TY[k]    = fmaxf(fmaf(x2, vwy12, fmaf(x1, vwy11, fmaf(x0, vwy10, vby1))), 0.f);
    }
    __syncthreads();
    // 7x7 SAME conv on (9,9), zero pad 3
    float ps = 0.f, pss = 0.f;
    const float vby7 = by7[0];
    for (int k = tid; k < NS; k += 512) {
      int bb = k / 81, p = k % 81, h = p / 9, w = p % 9;
      float acc = vby7;
      for (int kh = 0; kh < 7; ++kh) {
        int hh = h + kh - 3;
        if (hh < 0 || hh > 8) continue;
        for (int kw = 0; kw < 7; ++kw) {
          int wi = w + kw - 3;
          if (wi < 0 || wi > 8) continue;
          acc = fmaf(TY[bb*81 + hh*9 + wi], wy7[kh*7 + kw], acc);
        }
      }
      Y7[k] = acc;
      ps += acc; pss += acc*acc;
    }
    RED[tid] = ps; RED[512 + tid] = pss;
    __syncthreads();
    for (int off = 256; off > 0; off >>= 1) {
      if (tid < off) { RED[tid] += RED[tid + off]; RED[512 + tid] += RED[512 + tid + off]; }
      __syncthreads();
    }
    {
      float m  = RED[0]   * (1.f/5184.f);
      float v  = RED[512] * (1.f/5184.f) - m*m;
      float sc = bn_y_g[0] * rsqrtf(v + 1e-3f);
      float sh = bn_y_b[0] - m*sc;
      for (int k = tid; k < NS; k += 512) out[5*k + 3] = fmaf(Y7[k], sc, sh);
    }
    __syncthreads();
    // ---- z path ----  z1: 3x3 stride-3 conv (pad 0), bn, leaky 0.2
    if (tid < 128) RED[tid] = 0.f;
    __syncthreads();
    for (int k = tid; k < 6912; k += 512) {
      int bb = k / 108, r = k % 108, u = r / 36, v3 = (r / 12) % 3, oc = r % 12;
      float acc = 0.f;
      #pragma unroll
      for (int kh = 0; kh < 3; ++kh)
        #pragma unroll
        for (int kw = 0; kw < 3; ++kw) {
          const float* xp = x + (bb*81 + (3*u + kh)*9 + (3*v3 + kw))*3;
          #pragma unroll
          for (int cc = 0; cc < 3; ++cc)
            acc = fmaf(xp[cc], wd1[((kh*3 + kw)*3 + cc)*12 + oc], acc);
        }
      Z1[k] = acc;
    }
    __syncthreads();
    for (int k = tid; k < 6912; k += 512) {
      float v = Z1[k]; int oc = k % 12;
      atomicAdd(&RED[oc], v); atomicAdd(&RED[64 + oc], v*v);
    }
    __syncthreads();
    for (int k = tid; k < 6912; k += 512) {
      int oc = k % 12;
      float m  = RED[oc] * (1.f/576.f);
      float v  = RED[64 + oc] * (1.f/576.f) - m*m;
      float sc = bnd1_g[oc] * rsqrtf(v + 1e-3f);
      float z  = fmaf(Z1[k] - m, sc, bnd1_b[oc]);
      Z1[k] = z >= 0.f ? z : 0.2f*z;
    }
    __syncthreads();
    if (tid < 128) RED[tid] = 0.f;
    __syncthreads();
    for (int k = tid; k < 1536; k += 512) {      // z2: (3,3,12)->(1,1,24)
      int bb = k / 24, oc = k % 24;
      float acc = 0.f;
      for (int q = 0; q < 9; ++q)
        #pragma unroll
        for (int ic = 0; ic < 12; ++ic)
          acc = fmaf(Z1[bb*108 + q*12 + ic], wd2[(q*12 + ic)*24 + oc], acc);
      Z2[k] = acc;
    }
    __syncthreads();
    for (int k = tid; k < 1536; k += 512) {
      float v = Z2[k]; int oc = k % 24;
      atomicAdd(&RED[oc], v); atomicAdd(&RED[64 + oc], v*v);
    }
    __syncthreads();
    for (int k = tid; k < 1536; k += 512) {
      int oc = k % 24;
      float m  = RED[oc] * (1.f/64.f);
      float v  = RED[64 + oc] * (1.f/64.f) - m*m;
      float sc = bnd2_g[oc] * rsqrtf(v + 1e-3f);
      float z  = fmaf(Z2[k] - m, sc, bnd2_b[oc]);
      Z2[k] = z >= 0.f ? z : 0.2f*z;
    }
    __syncthreads();
    if (tid < 128) RED[tid] = 0.f;
    __syncthreads();
    // convT(z2, wu1): out[y,x,o] = sum_i z2[i] * wu1[2-y,2-x,i,o]
    for (int k = tid; k < 6912; k += 512) {
      int bb = k / 108, r = k % 108, yy = r / 36, xx = (r / 12) % 3, o = r % 12;
      const float* wpq = wu1 + ((2 - yy)*3 + (2 - xx))*288 + o;  // 288 = 24*12
      const float* zp = Z2 + bb*24;
      float acc = 0.f;
      #pragma unroll
      for (int i = 0; i < 24; ++i) acc = fmaf(zp[i], wpq[i*12], acc);
      ZU[k] = acc;
    }
    __syncthreads();
    for (int k = tid; k < 6912; k += 512) {
      float v = ZU[k]; int o = k % 12;
      atomicAdd(&RED[o], v); atomicAdd(&RED[64 + o], v*v);
    }
    __syncthreads();
    for (int k = tid; k < 6912; k += 512) {
      int o = k % 12;
      float m  = RED[o] * (1.f/576.f);
      float v  = RED[64 + o] * (1.f/576.f) - m*m;
      float sc = bnu1_g[o] * rsqrtf(v + 1e-3f);
      float z  = fmaf(ZU[k] - m, sc, bnu1_b[o]);
      ZU[k] = fmaxf(z, 0.f);
    }
    __syncthreads();
    // final convT(concat([zu, z1]), wu2)
    for (int k = tid; k < NS; k += 512) {
      int bb = k / 81, p = k % 81, h = p / 9, w = p % 9;
      int u = h / 3, v3 = w / 3, kh = 2 - (h % 3), kw = 2 - (w % 3);
      const float* wpp = wu2 + (kh*3 + kw)*24;
      const float* zu = ZU + bb*108 + u*36 + v3*12;
      const float* z1 = Z1 + bb*108 + u*36 + v3*12;
      float acc = 0.f;
      #pragma unroll
      for (int i = 0; i < 12; ++i) acc = fmaf(zu[i], wpp[i], acc);
      #pragma unroll
      for (int i = 0; i < 12; ++i) acc = fmaf(z1[i], wpp[12 + i], acc);
      out[5*k + 4] = fmaxf(acc, 0.f);
    }
  }
}

// ---------------------------------------------------------------------------
// K2 (384 thr): per-image x path. Planar LDS xin (row stride 73), rolled
// 5x5 tap loops, register-preloaded biases. conv5x5(reflect) -> maxpool4
// (SAME) -> 1x1+relu -> maxpool2 -> out channels 1,2.
// ---------------------------------------------------------------------------
__global__ __launch_bounds__(384) void cs_xpath(
    const float* __restrict__ ws_y, const float* __restrict__ bns,
    const float* __restrict__ bn_x_g, const float* __restrict__ bn_x_b,
    const float* __restrict__ w5, const float* __restrict__ b5,
    const float* __restrict__ wx2, const float* __restrict__ bx2,
    float* __restrict__ out)
{
  __shared__ __align__(16) float xin[3*5256 + 600];   // 3 planes (72 x stride 73) + w5s
  float* w5s = xin + 3*5256;
  const int tid = threadIdx.x, bb = blockIdx.x;

  const float N = 64.f * 73.f * 73.f;
  float sc[3], sh[3];
  #pragma unroll
  for (int c = 0; c < 3; ++c) {
    float m = bns[c]/N;
    float v = bns[3 + c]/N - m*m;
    sc[c] = bn_x_g[c]*rsqrtf(v + 1e-3f);
    sh[c] = bn_x_b[c] - m*sc[c];
  }
  #pragma unroll
  for (int c = 0; c < 3; ++c) {
    const float* src = ws_y + (bb*3 + c)*NS;
    float* dst = xin + c*5256;
    float s1 = sc[c], s2 = sh[c];
    for (int k = tid; k < NS; k += 384) {
      int h = k / 72, w = k - h*72;
      dst[h*73 + w] = fmaf(src[k], s1, s2);
    }
  }
  for (int k = tid; k < 600; k += 384) w5s[k] = w5[k];
  float b5r[8];
  #pragma unroll
  for (int o = 0; o < 8; ++o) b5r[o] = b5[o];
  __syncthreads();

  float mx[8];
  const bool active = tid < 324;   // 18*18 pooled cells, one per thread
  if (active) {
    int p = tid / 18, q = tid % 18;
    #pragma unroll
    for (int o = 0; o < 8; ++o) mx[o] = -1e30f;
    int r0 = 4*p - 1; if (r0 < 0) r0 = 0;
    int r1 = 4*p + 2; if (r1 > 68) r1 = 68;
    int c0 = 4*q - 1; if (c0 < 0) c0 = 0;
    int c1 = 4*q + 2; if (c1 > 68) c1 = 68;
    for (int r = r0; r <= r1; ++r) {
      for (int cc = c0; cc <= c1; ++cc) {
        float acc[8];
        #pragma unroll
        for (int o = 0; o < 8; ++o) acc[o] = b5r[o];
        #pragma unroll 1
        for (int kh = 0; kh < 5; ++kh) {
          int hs = r + kh - 1; hs = hs < 0 ? -hs : hs;   // reflect: |ph - 1|
          int rowb = hs*73;
          #pragma unroll 1
          for (int kw = 0; kw < 5; ++kw) {
            int wsc = cc + kw - 1; wsc = wsc < 0 ? -wsc : wsc;
            const float* wp = &w5s[(kh*5 + kw)*24];
            int a = rowb + wsc;
            float x0 = xin[a], x1 = xin[5256 + a], x2 = xin[2*5256 + a];
            #pragma unroll
            for (int o = 0; o < 8; ++o) {
              float t = fmaf(x0, wp[o], acc[o]);
              t = fmaf(x1, wp[8 + o], t);
              acc[o] = fmaf(x2, wp[16 + o], t);
            }
          }
        }
        #pragma unroll
        for (int o = 0; o < 8; ++o) mx[o] = fmaxf(mx[o], acc[o]);
      }
    }
  }
  __syncthreads();            // all conv reads of xin done
  float* pool = xin;          // reuse LDS: [ (p*18+q)*8 + o ]
  if (active) {
    int p = tid / 18, q = tid % 18;
    #pragma unroll
    for (int o = 0; o < 8; ++o) pool[(p*18 + q)*8 + o] = mx[o];
  }
  __syncthreads();
  if (tid < 162) {            // 81 pixels x 2 out channels
    int u = tid & 1, pix = tid >> 1;
    int h = pix / 9, w = pix % 9;
    float m = -1e30f;
    #pragma unroll
    for (int dp = 0; dp < 2; ++dp)
      #pragma unroll
      for (int dq = 0; dq < 2; ++dq) {
        int p = 2*h + dp, q = 2*w + dq;
        float acc = bx2[u];
        #pragma unroll
        for (int o = 0; o < 8; ++o) acc = fmaf(pool[(p*18 + q)*8 + o], wx2[o*2 + u], acc);
        m = fmaxf(m, fmaxf(acc, 0.f));
      }
    out[(bb*81 + pix)*5 + 1 + u] = m;
  }
}

extern "C" void kernel_launch(void* const* d_in, const int* in_sizes, int n_in,
                              void* d_out, int out_size, void* d_ws, size_t ws_size,
                              hipStream_t stream) {
  (void)in_sizes; (void)n_in; (void)out_size; (void)ws_size;
  const float* x      = (const float*)d_in[0];
  const float* mat    = (const float*)d_in[1];
  const float* bn_x_g = (const float*)d_in[2];
  const float* bn_x_b = (const float*)d_in[3];
  const float* w5     = (const float*)d_in[4];
  const float* b5     = (const float*)d_in[5];
  const float* wx2    = (const float*)d_in[6];
  const float* bx2    = (const float*)d_in[7];
  const float* wy1    = (const float*)d_in[8];
  const float* by1    = (const float*)d_in[9];
  const float* wy7    = (const float*)d_in[10];
  const float* by7    = (const float*)d_in[11];
  const float* bn_y_g = (const float*)d_in[12];
  const float* bn_y_b = (const float*)d_in[13];
  const float* ww1    = (const float*)d_in[14];
  const float* bw1    = (const float*)d_in[15];
  const float* wd1    = (const float*)d_in[16];
  const float* bnd1_g = (const float*)d_in[17];
  const float* bnd1_b = (const float*)d_in[18];
  const float* wd2    = (const float*)d_in[19];
  const float* bnd2_g = (const float*)d_in[20];
  const float* bnd2_b = (const float*)d_in[21];
  const float* wu1    = (const float*)d_in[22];
  const float* bnu1_g = (const float*)d_in[23];
  const float* bnu1_b = (const float*)d_in[24];
  const float* wu2    = (const float*)d_in[25];

  float* outp = (float*)d_out;
  float* ws_y = (float*)d_ws;                 // planar: 64*3*5184 floats
  float* bns  = ws_y + 64*3*5184;             // 6 floats: sum[3], sumsq[3]

  hipMemsetAsync(bns, 0, 6*sizeof(float), stream);
  cs_fista_small<<<dim3(193), dim3(512), 0, stream>>>(
      x, mat, wy1, by1, wy7, by7, bn_y_g, bn_y_b, ww1, bw1,
      wd1, bnd1_g, bnd1_b, wd2, bnd2_g, bnd2_b, wu1, bnu1_g, bnu1_b, wu2,
      ws_y, bns, outp);
  cs_xpath<<<dim3(64), dim3(384), 0, stream>>>(
      ws_y, bns, bn_x_g, bn_x_b, w5, b5, wx2, bx2, outp);
}

// Round 7
// 321.438 us; speedup vs baseline: 3.0795x; 1.3248x over previous
//
#include <hip/hip_runtime.h>
#include <hip/hip_bf16.h>
#include <math.h>

#define NS 5184   // 72*72

// ---------------------------------------------------------------------------
// K1 (576 thr = 9 waves): blocks 0..191 = FISTA, one (batch,channel) chain
// per block. Register-resident state: thread (a=tid/8, slot=tid%8) owns
// y[a][slot*9 .. slot*9+9) and its private 9x9 gp block (constant).
// Per iter (4 barriers):
//   A : pj[j] = sum_bl ym[bl]*g_blk[bl][j]      (regs) -> PART (LDS)
//   B : W1T[j][a] = sum_slot PART[a][slot][j]   (648 thr)
//   C : M9[i][j] = sum_a GT[i][a]*W1T[j][a]     (81 thr, float4 dots)
//   C2: T2L[a][j] = GIM[a][j] - sum_i GT[i][a]*M9[i][j]  (648 thr)
//   D : re = sum_j T2L[a][j]*g_blk[bl][j]; shrink+momentum (regs)
// block 192 = small paths (w, y, z) independent of FISTA.
// ---------------------------------------------------------------------------
__global__ __launch_bounds__(576, 3) void cs_fista_small(
    const float* __restrict__ x, const float* __restrict__ mat,
    const float* __restrict__ wy1, const float* __restrict__ by1,
    const float* __restrict__ wy7, const float* __restrict__ by7,
    const float* __restrict__ bn_y_g, const float* __restrict__ bn_y_b,
    const float* __restrict__ ww1, const float* __restrict__ bw1,
    const float* __restrict__ wd1, const float* __restrict__ bnd1_g, const float* __restrict__ bnd1_b,
    const float* __restrict__ wd2, const float* __restrict__ bnd2_g, const float* __restrict__ bnd2_b,
    const float* __restrict__ wu1, const float* __restrict__ bnu1_g, const float* __restrict__ bnu1_b,
    const float* __restrict__ wu2,
    float* __restrict__ ws_y, float* __restrict__ bns, float* __restrict__ out)
{
  __shared__ __align__(16) float smem[16384];   // 64 KB
  const int tid = threadIdx.x;
  const int blk = blockIdx.x;

  if (blk < 192) {
    // ------------------------- FISTA -------------------------
    const int bb = blk / 3, ch = blk % 3;
    float* PART = smem;            // 5184  [a][slot][j]
    float* W1T  = smem + 5184;     // 9*76  [j][a] pad 76
    float* GT   = smem + 5868;     // 9*76  [i][a] pad 76
    float* M9   = smem + 6552;     // 81    [i*9+j]
    float* T2L  = smem + 6633;     // 72*12 [a*12+j]
    float* GIM  = smem + 7497;     // 648   [a*9+j]
    float* IM   = smem + 8145;     // 81
    float* RED  = smem + 8226;     // 32

    const int a    = tid >> 3;     // 0..71
    const int slot = tid & 7;      // 0..7
    const int b0   = slot * 9;

    // ---- setup ----
    for (int k = tid; k < 648; k += 576) {
      int aa = k / 9, i = k % 9;
      // mat[(a,a),(i,i)] = gp[a,i]^2 exactly (Kronecker structure, gp > 0)
      GT[i*76 + aa] = sqrtf(mat[aa*5913 + i*10]);
    }
    if (tid < 81) IM[tid] = x[(bb*81 + tid)*3 + ch];
    __syncthreads();
    for (int k = tid; k < 648; k += 576) {       // GIM = G * IM
      int aa = k / 9, j = k % 9;
      float acc = 0.f;
      #pragma unroll
      for (int i = 0; i < 9; ++i) acc = fmaf(GT[i*76 + aa], IM[i*9 + j], acc);
      GIM[aa*9 + j] = acc;
    }
    float g_blk[9][9];                           // private gp rows (constant)
    #pragma unroll
    for (int bl = 0; bl < 9; ++bl)
      #pragma unroll
      for (int j = 0; j < 9; ++j)
        g_blk[bl][j] = sqrtf(mat[(b0 + bl)*5913 + j*10]);
    float ym[9], yl[9];
    #pragma unroll
    for (int bl = 0; bl < 9; ++bl) { ym[bl] = 0.f; yl[bl] = 0.f; }
    __syncthreads();

    float t = 1.f;
    for (int it = 0; it < 100; ++it) {
      // ---- A: partials from register state ----
      {
        float* pp = PART + a*72 + slot*9;
        #pragma unroll
        for (int j = 0; j < 9; ++j) {
          float acc = 0.f;
          #pragma unroll
          for (int bl = 0; bl < 9; ++bl) acc = fmaf(ym[bl], g_blk[bl][j], acc);
          pp[j] = acc;
        }
      }
      __syncthreads();
      // ---- B: reduce partials -> W1T ----
      for (int k = tid; k < 648; k += 576) {
        int aa = k / 9, j = k % 9;
        const float* pp = PART + aa*72 + j;
        float s01 = pp[0] + pp[9],   s23 = pp[18] + pp[27];
        float s45 = pp[36] + pp[45], s67 = pp[54] + pp[63];
        W1T[j*76 + aa] = (s01 + s23) + (s45 + s67);
      }
      __syncthreads();
      // ---- C: M9[i][j] = dot72(GT row i, W1T row j) ----
      if (tid < 81) {
        int i = tid / 9, jj = tid % 9;
        const float4* gr = (const float4*)(GT + i*76);
        const float4* wr = (const float4*)(W1T + jj*76);
        float p0=0,p1=0,p2=0,p3=0,p4=0,p5=0,p6=0,p7=0;
        #pragma unroll
        for (int q = 0; q < 18; q += 2) {
          float4 g0 = gr[q],   w0 = wr[q];
          float4 g1 = gr[q+1], w1 = wr[q+1];
          p0 = fmaf(g0.x, w0.x, p0); p1 = fmaf(g0.y, w0.y, p1);
          p2 = fmaf(g0.z, w0.z, p2); p3 = fmaf(g0.w, w0.w, p3);
          p4 = fmaf(g1.x, w1.x, p4); p5 = fmaf(g1.y, w1.y, p5);
          p6 = fmaf(g1.z, w1.z, p6); p7 = fmaf(g1.w, w1.w, p7);
        }
        M9[tid] = ((p0+p1)+(p2+p3)) + ((p4+p5)+(p6+p7));
      }
      __syncthreads();
      // ---- C2: T2L[a][j] = GIM[a][j] - sum_i GT[i][a]*M9[i][j] ----
      for (int k = tid; k < 648; k += 576) {
        int aa = k / 9, j = k % 9;
        float acc = GIM[aa*9 + j];
        #pragma unroll
        for (int i = 0; i < 9; ++i) acc = fmaf(-GT[i*76 + aa], M9[i*9 + j], acc);
        T2L[aa*12 + j] = acc;
      }
      __syncthreads();
      // ---- D: re + shrink + momentum, all in regs ----
      const float tn  = 0.5f * (1.f + sqrtf(1.f + 4.f*t*t));
      const float mom = (t - 1.f) / tn;
      float t2r[9];
      #pragma unroll
      for (int j = 0; j < 9; ++j) t2r[j] = T2L[a*12 + j];
      #pragma unroll
      for (int bl = 0; bl < 9; ++bl) {
        float re = 0.f;
        #pragma unroll
        for (int j = 0; j < 9; ++j) re = fmaf(t2r[j], g_blk[bl][j], re);
        float w  = ym[bl] + re;                      // MU = 1
        float yn = fmaxf(w - 0.005f, 0.f) - fmaxf(-w - 0.005f, 0.f);
        float y2 = fmaf(mom, yn - yl[bl], yn);
        yl[bl] = yn;
        ym[bl] = y2;
      }
      t = tn;
      // next A's PART writes are fenced from this iter's B reads by 3 barriers
    }
    // ---- epilogue: yl = y_final; planar write + reflect-weighted stats ----
    float* wp = ws_y + (bb*3 + ch)*NS + a*72 + b0;
    float wsum = 0.f, wss = 0.f;
    #pragma unroll
    for (int bl = 0; bl < 9; ++bl) {
      wp[bl] = yl[bl];
      float wt = (float)((1 + (a == 1)) * (1 + (b0 + bl == 1)));  // reflect multiplicity
      wsum = fmaf(wt, yl[bl], wsum);
      wss  = fmaf(wt * yl[bl], yl[bl], wss);
    }
    #pragma unroll
    for (int off = 32; off > 0; off >>= 1) {
      wsum += __shfl_down(wsum, off);
      wss  += __shfl_down(wss, off);
    }
    if ((tid & 63) == 0) { RED[tid >> 6] = wsum; RED[16 + (tid >> 6)] = wss; }
    __syncthreads();
    if (tid == 0) {
      float s = 0.f, s2 = 0.f;
      for (int w = 0; w < 9; ++w) { s += RED[w]; s2 += RED[16 + w]; }
      atomicAdd(&bns[ch],     s);
      atomicAdd(&bns[3 + ch], s2);
    }
  } else {
    // ------------------------- small paths (w, y, z) -------------------------
    float* TY  = smem;           // 5184
    float* Y7  = smem + 5184;    // 5184
    float* Z1  = smem;           // 6912  (reuses TY/Y7 after y path)
    float* Z2  = smem + 6912;    // 1536
    float* ZU  = smem + 8448;    // 6912
    float* RED = smem + 15360;   // 128 (z-path stats) + reuse [0..33] for y-path

    const float vwy10 = wy1[0], vwy11 = wy1[1], vwy12 = wy1[2], vby1 = by1[0];
    const float vww10 = ww1[0], vww11 = ww1[1], vww12 = ww1[2], vbw1 = bw1[0];
    for (int k = tid; k < NS; k += 576) {
      const float* xp = x + 3*k;
      float x0 = xp[0], x1 = xp[1], x2 = xp[2];
      out[5*k] = fmaxf(fmaf(x2, vww12, fmaf(x1, vww11, fmaf(x0, vww10, vbw1))), 0.f);
      TY[k]    = fmaxf(fmaf(x2, vwy12, fmaf(x1, vwy11, fmaf(x0, vwy10, vby1))), 0.f);
    }
    __syncthreads();
    // 7x7 SAME conv on (9,9), zero pad 3
    float ps = 0.f, pss = 0.f;
    const float vby7 = by7[0];
    for (int k = tid; k < NS; k += 576) {
      int bb = k / 81, p = k % 81, h = p / 9, w = p % 9;
      float acc = vby7;
      for (int kh = 0; kh < 7; ++kh) {
        int hh = h + kh - 3;
        if (hh < 0 || hh > 8) continue;
        for (int kw = 0; kw < 7; ++kw) {
          int wi = w + kw - 3;
          if (wi < 0 || wi > 8) continue;
          acc = fmaf(TY[bb*81 + hh*9 + wi], wy7[kh*7 + kw], acc);
        }
      }
      Y7[k] = acc;
      ps += acc; pss += acc*acc;
    }
    #pragma unroll
    for (int off = 32; off > 0; off >>= 1) {
      ps  += __shfl_down(ps, off);
      pss += __shfl_down(pss, off);
    }
    if ((tid & 63) == 0) { RED[tid >> 6] = ps; RED[16 + (tid >> 6)] = pss; }
    __syncthreads();
    if (tid == 0) {
      float s = 0.f, s2 = 0.f;
      for (int w = 0; w < 9; ++w) { s += RED[w]; s2 += RED[16 + w]; }
      float m  = s  * (1.f/5184.f);
      float v  = s2 * (1.f/5184.f) - m*m;
      float sc = bn_y_g[0] * rsqrtf(v + 1e-3f);
      RED[32] = sc;
      RED[33] = bn_y_b[0] - m*sc;
    }
    __syncthreads();
    {
      float sc = RED[32], sh = RED[33];
      for (int k = tid; k < NS; k += 576) out[5*k + 3] = fmaf(Y7[k], sc, sh);
    }
    __syncthreads();
    // ---- z path ----  z1: 3x3 stride-3 conv (pad 0), bn, leaky 0.2
    if (tid < 128) RED[tid] = 0.f;
    __syncthreads();
    for (int k = tid; k < 6912; k += 576) {
      int bb = k / 108, r = k % 108, u = r / 36, v3 = (r / 12) % 3, oc = r % 12;
      float acc = 0.f;
      #pragma unroll
      for (int kh = 0; kh < 3; ++kh)
        #pragma unroll
        for (int kw = 0; kw < 3; ++kw) {
          const float* xp = x + (bb*81 + (3*u + kh)*9 + (3*v3 + kw))*3;
          #pragma unroll
          for (int cc = 0; cc < 3; ++cc)
            acc = fmaf(xp[cc], wd1[((kh*3 + kw)*3 + cc)*12 + oc], acc);
        }
      Z1[k] = acc;
    }
    __syncthreads();
    for (int k = tid; k < 6912; k += 576) {
      float v = Z1[k]; int oc = k % 12;
      atomicAdd(&RED[oc], v); atomicAdd(&RED[64 + oc], v*v);
    }
    __syncthreads();
    for (int k = tid; k < 6912; k += 576) {
      int oc = k % 12;
      float m  = RED[oc] * (1.f/576.f);
      float v  = RED[64 + oc] * (1.f/576.f) - m*m;
      float sc = bnd1_g[oc] * rsqrtf(v + 1e-3f);
      float z  = fmaf(Z1[k] - m, sc, bnd1_b[oc]);
      Z1[k] = z >= 0.f ? z : 0.2f*z;
    }
    __syncthreads();
    if (tid < 128) RED[tid] = 0.f;
    __syncthreads();
    for (int k = tid; k < 1536; k += 576) {      // z2: (3,3,12)->(1,1,24)
      int bb = k / 24, oc = k % 24;
      float acc = 0.f;
      for (int q = 0; q < 9; ++q)
        #pragma unroll
        for (int ic = 0; ic < 12; ++ic)
          acc = fmaf(Z1[bb*108 + q*12 + ic], wd2[(q*12 + ic)*24 + oc], acc);
      Z2[k] = acc;
    }
    __syncthreads();
    for (int k = tid; k < 1536; k += 576) {
      float v = Z2[k]; int oc = k % 24;
      atomicAdd(&RED[oc], v); atomicAdd(&RED[64 + oc], v*v);
    }
    __syncthreads();
    for (int k = tid; k < 1536; k += 576) {
      int oc = k % 24;
      float m  = RED[oc] * (1.f/64.f);
      float v  = RED[64 + oc] * (1.f/64.f) - m*m;
      float sc = bnd2_g[oc] * rsqrtf(v + 1e-3f);
      float z  = fmaf(Z2[k] - m, sc, bnd2_b[oc]);
      Z2[k] = z >= 0.f ? z : 0.2f*z;
    }
    __syncthreads();
    if (tid < 128) RED[tid] = 0.f;
    __syncthreads();
    // convT(z2, wu1): out[y,x,o] = sum_i z2[i] * wu1[2-y,2-x,i,o]
    for (int k = tid; k < 6912; k += 576) {
      int bb = k / 108, r = k % 108, yy = r / 36, xx = (r / 12) % 3, o = r % 12;
      const float* wpq = wu1 + ((2 - yy)*3 + (2 - xx))*288 + o;  // 288 = 24*12
      const float* zp = Z2 + bb*24;
      float acc = 0.f;
      #pragma unroll
      for (int i = 0; i < 24; ++i) acc = fmaf(zp[i], wpq[i*12], acc);
      ZU[k] = acc;
    }
    __syncthreads();
    for (int k = tid; k < 6912; k += 576) {
      float v = ZU[k]; int o = k % 12;
      atomicAdd(&RED[o], v); atomicAdd(&RED[64 + o], v*v);
    }
    __syncthreads();
    for (int k = tid; k < 6912; k += 576) {
      int o = k % 12;
      float m  = RED[o] * (1.f/576.f);
      float v  = RED[64 + o] * (1.f/576.f) - m*m;
      float sc = bnu1_g[o] * rsqrtf(v + 1e-3f);
      float z  = fmaf(ZU[k] - m, sc, bnu1_b[o]);
      ZU[k] = fmaxf(z, 0.f);
    }
    __syncthreads();
    // final convT(concat([zu, z1]), wu2)
    for (int k = tid; k < NS; k += 576) {
      int bb = k / 81, p = k % 81, h = p / 9, w = p % 9;
      int u = h / 3, v3 = w / 3, kh = 2 - (h % 3), kw = 2 - (w % 3);
      const float* wpp = wu2 + (kh*3 + kw)*24;
      const float* zu = ZU + bb*108 + u*36 + v3*12;
      const float* z1 = Z1 + bb*108 + u*36 + v3*12;
      float acc = 0.f;
      #pragma unroll
      for (int i = 0; i < 12; ++i) acc = fmaf(zu[i], wpp[i], acc);
      #pragma unroll
      for (int i = 0; i < 12; ++i) acc = fmaf(z1[i], wpp[12 + i], acc);
      out[5*k + 4] = fmaxf(acc, 0.f);
    }
  }
}

// ---------------------------------------------------------------------------
// K2 (384 thr): per-image x path. Planar LDS xin (row stride 73), rolled
// 5x5 tap loops, register-preloaded biases. conv5x5(reflect) -> maxpool4
// (SAME) -> 1x1+relu -> maxpool2 -> out channels 1,2.
// ---------------------------------------------------------------------------
__global__ __launch_bounds__(384) void cs_xpath(
    const float* __restrict__ ws_y, const float* __restrict__ bns,
    const float* __restrict__ bn_x_g, const float* __restrict__ bn_x_b,
    const float* __restrict__ w5, const float* __restrict__ b5,
    const float* __restrict__ wx2, const float* __restrict__ bx2,
    float* __restrict__ out)
{
  __shared__ __align__(16) float xin[3*5256 + 600];   // 3 planes (72 x stride 73) + w5s
  float* w5s = xin + 3*5256;
  const int tid = threadIdx.x, bb = blockIdx.x;

  const float N = 64.f * 73.f * 73.f;
  float sc[3], sh[3];
  #pragma unroll
  for (int c = 0; c < 3; ++c) {
    float m = bns[c]/N;
    float v = bns[3 + c]/N - m*m;
    sc[c] = bn_x_g[c]*rsqrtf(v + 1e-3f);
    sh[c] = bn_x_b[c] - m*sc[c];
  }
  #pragma unroll
  for (int c = 0; c < 3; ++c) {
    const float* src = ws_y + (bb*3 + c)*NS;
    float* dst = xin + c*5256;
    float s1 = sc[c], s2 = sh[c];
    for (int k = tid; k < NS; k += 384) {
      int h = k / 72, w = k - h*72;
      dst[h*73 + w] = fmaf(src[k], s1, s2);
    }
  }
  for (int k = tid; k < 600; k += 384) w5s[k] = w5[k];
  float b5r[8];
  #pragma unroll
  for (int o = 0; o < 8; ++o) b5r[o] = b5[o];
  __syncthreads();

  float mx[8];
  const bool active = tid < 324;   // 18*18 pooled cells, one per thread
  if (active) {
    int p = tid / 18, q = tid % 18;
    #pragma unroll
    for (int o = 0; o < 8; ++o) mx[o] = -1e30f;
    int r0 = 4*p - 1; if (r0 < 0) r0 = 0;
    int r1 = 4*p + 2; if (r1 > 68) r1 = 68;
    int c0 = 4*q - 1; if (c0 < 0) c0 = 0;
    int c1 = 4*q + 2; if (c1 > 68) c1 = 68;
    for (int r = r0; r <= r1; ++r) {
      for (int cc = c0; cc <= c1; ++cc) {
        float acc[8];
        #pragma unroll
        for (int o = 0; o < 8; ++o) acc[o] = b5r[o];
        #pragma unroll 1
        for (int kh = 0; kh < 5; ++kh) {
          int hs = r + kh - 1; hs = hs < 0 ? -hs : hs;   // reflect: |ph - 1|
          int rowb = hs*73;
          #pragma unroll 1
          for (int kw = 0; kw < 5; ++kw) {
            int wsc = cc + kw - 1; wsc = wsc < 0 ? -wsc : wsc;
            const float* wp = &w5s[(kh*5 + kw)*24];
            int aI = rowb + wsc;
            float x0 = xin[aI], x1 = xin[5256 + aI], x2 = xin[2*5256 + aI];
            #pragma unroll
            for (int o = 0; o < 8; ++o) {
              float t = fmaf(x0, wp[o], acc[o]);
              t = fmaf(x1, wp[8 + o], t);
              acc[o] = fmaf(x2, wp[16 + o], t);
            }
          }
        }
        #pragma unroll
        for (int o = 0; o < 8; ++o) mx[o] = fmaxf(mx[o], acc[o]);
      }
    }
  }
  __syncthreads();            // all conv reads of xin done
  float* pool = xin;          // reuse LDS: [ (p*18+q)*8 + o ]
  if (active) {
    int p = tid / 18, q = tid % 18;
    #pragma unroll
    for (int o = 0; o < 8; ++o) pool[(p*18 + q)*8 + o] = mx[o];
  }
  __syncthreads();
  if (tid < 162) {            // 81 pixels x 2 out channels
    int u = tid & 1, pix = tid >> 1;
    int h = pix / 9, w = pix % 9;
    float m = -1e30f;
    #pragma unroll
    for (int dp = 0; dp < 2; ++dp)
      #pragma unroll
      for (int dq = 0; dq < 2; ++dq) {
        int p = 2*h + dp, q = 2*w + dq;
        float acc = bx2[u];
        #pragma unroll
        for (int o = 0; o < 8; ++o) acc = fmaf(pool[(p*18 + q)*8 + o], wx2[o*2 + u], acc);
        m = fmaxf(m, fmaxf(acc, 0.f));
      }
    out[(bb*81 + pix)*5 + 1 + u] = m;
  }
}

extern "C" void kernel_launch(void* const* d_in, const int* in_sizes, int n_in,
                              void* d_out, int out_size, void* d_ws, size_t ws_size,
                              hipStream_t stream) {
  (void)in_sizes; (void)n_in; (void)out_size; (void)ws_size;
  const float* x      = (const float*)d_in[0];
  const float* mat    = (const float*)d_in[1];
  const float* bn_x_g = (const float*)d_in[2];
  const float* bn_x_b = (const float*)d_in[3];
  const float* w5     = (const float*)d_in[4];
  const float* b5     = (const float*)d_in[5];
  const float* wx2    = (const float*)d_in[6];
  const float* bx2    = (const float*)d_in[7];
  const float* wy1    = (const float*)d_in[8];
  const float* by1    = (const float*)d_in[9];
  const float* wy7    = (const float*)d_in[10];
  const float* by7    = (const float*)d_in[11];
  const float* bn_y_g = (const float*)d_in[12];
  const float* bn_y_b = (const float*)d_in[13];
  const float* ww1    = (const float*)d_in[14];
  const float* bw1    = (const float*)d_in[15];
  const float* wd1    = (const float*)d_in[16];
  const float* bnd1_g = (const float*)d_in[17];
  const float* bnd1_b = (const float*)d_in[18];
  const float* wd2    = (const float*)d_in[19];
  const float* bnd2_g = (const float*)d_in[20];
  const float* bnd2_b = (const float*)d_in[21];
  const float* wu1    = (const float*)d_in[22];
  const float* bnu1_g = (const float*)d_in[23];
  const float* bnu1_b = (const float*)d_in[24];
  const float* wu2    = (const float*)d_in[25];

  float* outp = (float*)d_out;
  float* ws_y = (float*)d_ws;                 // planar: 64*3*5184 floats
  float* bns  = ws_y + 64*3*5184;             // 6 floats: sum[3], sumsq[3]

  hipMemsetAsync(bns, 0, 6*sizeof(float), stream);
  cs_fista_small<<<dim3(193), dim3(576), 0, stream>>>(
      x, mat, wy1, by1, wy7, by7, bn_y_g, bn_y_b, ww1, bw1,
      wd1, bnd1_g, bnd1_b, wd2, bnd2_g, bnd2_b, wu1, bnu1_g, bnu1_b, wu2,
      ws_y, bns, outp);
  cs_xpath<<<dim3(64), dim3(384), 0, stream>>>(
      ws_y, bns, bn_x_g, bn_x_b, w5, b5, wx2, bx2, outp);
}